// Round 10
// baseline (504.739 us; speedup 1.0000x reference)
//
#include <hip/hip_runtime.h>
#include <hip/hip_cooperative_groups.h>

namespace cg = cooperative_groups;

#define N_NODES 10242
#define NNZ_E   71694
// rows padded to multiple of 8, +64 slack for cooperative over-read
#define NNZ_PAD_MAX (NNZ_E + 7 * N_NODES + 64)
#define BT      32      // B*T
#define C_IN    16
#define K_S     20
#define C_OUT   32
#define F       512     // BT * C_IN
typedef unsigned short u16;
typedef unsigned int   u32;
typedef unsigned long long u64;

#define RING_ELEMS ((size_t)N_NODES * F)    // f16 elems per ring slot, layout [n][bt*16+c]
#define RING_BYTES (RING_ELEMS * 2)         // ~10.5 MB

#define OVFL_FLAG (1 << 30)

typedef __attribute__((ext_vector_type(8)))  _Float16 half8;
typedef __attribute__((ext_vector_type(16))) float    float16;

__device__ __forceinline__ void unpack8h(uint4 u, float* f) {
    union { uint4 u; _Float16 h[8]; } v; v.u = u;
    #pragma unroll
    for (int i = 0; i < 8; ++i) f[i] = (float)v.h[i];
}
__device__ __forceinline__ uint4 pack8h(const float* f) {
    union { uint4 u; _Float16 h[8]; } v;
    #pragma unroll
    for (int i = 0; i < 8; ++i) v.h[i] = (_Float16)f[i];
    return v.u;
}
__device__ __forceinline__ u16 f2h(float f) {
    union { _Float16 h; u16 u; } v; v.h = (_Float16)f; return v.u;
}

// ---------------- parallel CSR build (5 small wide-grid kernels) -----------
// Determinism: per-row (col,valbits) multiset is fixed; rank-sort by
// (col,valbits,pos) makes the CSR (and f32 accumulation order) deterministic.
// Rows padded to x8 with (col=0,val=0) entries (contribute exactly 0).

__global__ __launch_bounds__(256) void init_kernel(
        const float* __restrict__ W, int* __restrict__ cnt,
        u16* __restrict__ wtfrag, int* __restrict__ syncp) {
    int i = blockIdx.x * 256 + threadIdx.x;
    if (i < N_NODES) cnt[i] = 0;
    if (i < 16) syncp[i] = 0;
    int w = i - N_NODES;
    if (w >= 0 && w < K_S * 64 * 8) {
        // B-frag for v_mfma_f32_32x32x16_f16: lane L, reg j ->
        // B[k=8*(L>>5)+j][col=L&31] = W[cout=col][c=k][k_cheb]
        int j    = w & 7;
        int lane = (w >> 3) & 63;
        int k    = w >> 9;
        int cout = lane & 31;
        int c    = ((lane >> 5) << 3) + j;
        wtfrag[w] = f2h(W[cout * (C_IN * K_S) + c * K_S + k]);
    }
}

__global__ __launch_bounds__(256) void count_kernel(
        const int* __restrict__ erow, int* cnt) {
    int e = blockIdx.x * 256 + threadIdx.x;
    if (e < NNZ_E) atomicAdd(&cnt[erow[e]], 1);
}

__global__ __launch_bounds__(256) void scan_kernel(
        const int* __restrict__ cnt, int* row_ptr, int* cursor) {
    const int T = 256;
    const int chunk = (N_NODES + T - 1) / T;  // 41
    __shared__ int part[T];
    int t = threadIdx.x;
    int base = t * chunk;
    int s = 0;
    for (int i = 0; i < chunk; ++i) {
        int idx = base + i;
        if (idx < N_NODES) s += (cnt[idx] + 7) & ~7;
    }
    part[t] = s;
    __syncthreads();
    for (int off = 1; off < T; off <<= 1) {
        int v = (t >= off) ? part[t - off] : 0;
        __syncthreads();
        part[t] += v;
        __syncthreads();
    }
    int run = (t == 0) ? 0 : part[t - 1];
    for (int i = 0; i < chunk; ++i) {
        int idx = base + i;
        if (idx < N_NODES) {
            row_ptr[idx] = run;
            cursor[idx]  = run;
            run += (cnt[idx] + 7) & ~7;
        }
    }
    if (t == T - 1) row_ptr[N_NODES] = part[T - 1];
}

__global__ __launch_bounds__(256) void scatter_kernel(
        const int* __restrict__ erow, const int* __restrict__ ecol,
        const float* __restrict__ eval, int* cursor, int2* __restrict__ cpack) {
    int e = blockIdx.x * 256 + threadIdx.x;
    if (e < NNZ_E) {
        int p = atomicAdd(&cursor[erow[e]], 1);
        cpack[p] = make_int2(ecol[e], __float_as_int(eval[e]));
    }
}

// wave-per-row rank sort + pad + fixed-16 pack (round-8 proven)
__global__ __launch_bounds__(256) void finalize_kernel(
        const int* __restrict__ row_ptr, const int* __restrict__ cursor,
        int2* cpack, int2* __restrict__ epk16) {
    const int lane = threadIdx.x & 63;
    const int r = (blockIdx.x << 2) + (threadIdx.x >> 6);
    if (r >= N_NODES) return;
    const int sbeg = row_ptr[r];
    const int send = cursor[r];      // sbeg + real count
    const int pend = row_ptr[r + 1]; // sbeg + padded count
    const int rlen = send - sbeg;
    const int plen = pend - sbeg;

    if (plen > 64) {                 // essentially impossible; serial fallback
        if (lane == 0) {
            for (int i = sbeg + 1; i < send; ++i) {
                int2 key = cpack[i];
                int j = i - 1;
                while (j >= sbeg) {
                    int2 q = cpack[j];
                    bool gt = (q.x > key.x) || (q.x == key.x && (u32)q.y > (u32)key.y);
                    if (!gt) break;
                    cpack[j + 1] = q; --j;
                }
                cpack[j + 1] = key;
            }
            for (int p = send; p < pend; ++p) cpack[p] = make_int2(0, 0);
            for (int p = 0; p < 16; ++p) {
                int2 v = (p < plen) ? cpack[sbeg + p] : make_int2(0, 0);
                if (p == 15 && rlen > 16) v.x |= OVFL_FLAG;
                epk16[(size_t)r * 16 + p] = v;
            }
        }
        return;
    }

    const bool real = (lane < rlen);
    int2 e = real ? cpack[sbeg + lane] : make_int2(0, 0);
    const u64 ki = ((u64)(u32)e.x << 32) | (u32)e.y;

    int rank = 0;
    for (int j = 0; j < rlen; ++j) {
        int cx = __shfl(e.x, j, 64);
        int cy = __shfl(e.y, j, 64);
        u64 kj = ((u64)(u32)cx << 32) | (u32)cy;
        if (kj < ki || (kj == ki && j < lane)) ++rank;
    }
    if (!real) rank = lane;

    if (lane < plen) cpack[sbeg + rank] = real ? e : make_int2(0, 0);

    int2 v16 = real ? e : make_int2(0, 0);
    if (rank == 15 && rlen > 16) v16.x |= OVFL_FLAG;
    if (rank < 16) epk16[(size_t)r * 16 + rank] = v16;
}

// ---------------- per-XCD BSP barrier --------------------------------------
// Monotonic counter; RELAXED atomics only (no L2-invalidating acquire).
// Producer stores are write-through into the XCD's L2 and drained by the
// explicit vmcnt(0) before the counter increment; consumers' plain loads
// then read current L2 data. Stale L1 is structurally impossible: every ring
// slot is write-once-then-read (no reuse), so no consumer L1 line can predate
// its producing write.

__device__ __forceinline__ void xbar(int* sync, int xcc, int nb, int target_mult) {
    asm volatile("s_waitcnt vmcnt(0)" ::: "memory");
    __syncthreads();
    if (threadIdx.x == 0) {
        __hip_atomic_fetch_add(&sync[8 + xcc], 1, __ATOMIC_RELAXED,
                               __HIP_MEMORY_SCOPE_AGENT);
        const int tgt = target_mult * nb;
        while (__hip_atomic_load(&sync[8 + xcc], __ATOMIC_RELAXED,
                                 __HIP_MEMORY_SCOPE_AGENT) < tgt)
            __builtin_amdgcn_s_sleep(16);
    }
    __syncthreads();
    asm volatile("" ::: "memory");
}

// ---------------- persistent sliced Chebyshev chain (cooperative) ----------
// Blocks on physical XCD j exclusively own column slice j (64 of 512 cols):
// ALL ring traffic for a slice stays in that XCD's L2 across all 19 steps —
// no dispatch-boundary flushes, no cross-XCD coherence needed (slice-private
// data + write-once slots). PLAIN loads (L1/L2 hit path) — round 9 proved
// sc0 agent-scope loads bypass the non-coherent L2 straight to HBM.
// Per-XCD BSP barriers between steps. 80KB LDS forces 1 block/CU.

__global__ __launch_bounds__(1024) void chain_bsp_kernel(
        const float* __restrict__ x,
        const int* __restrict__ row_ptr, const int2* __restrict__ cpack,
        const int2* __restrict__ epk16,
        u16* __restrict__ ring, int* __restrict__ sync) {
    __shared__ int shv[2];
    __shared__ char lds_force[81920];
    cg::grid_group grid = cg::this_grid();

    if (threadIdx.x == 0) {
        ((volatile char*)lds_force)[0] = 0;
        // HW_REG_XCC_ID (id=20), offset 0, size 32
        int xcc = __builtin_amdgcn_s_getreg((31 << 11) | (0 << 6) | 20) & 7;
        shv[0] = xcc;
        shv[1] = atomicAdd(&sync[xcc], 1);   // rank within this XCD
    }
    __syncthreads();
    const int xcc  = shv[0];
    const int rank = shv[1];
    grid.sync();                              // registration complete
    const int nb = sync[xcc];                 // blocks on this XCD

    const int w     = threadIdx.x >> 6;
    const int l     = threadIdx.x & 63;
    const int g     = l >> 3;
    const int gl    = l & 7;
    const int gbase = l & 56;
    const int f0    = xcc << 6;               // 64-col slice base

    const int chunk = (N_NODES + nb - 1) / nb;
    const int n0 = rank * chunk;
    int n1 = n0 + chunk; if (n1 > N_NODES) n1 = N_NODES;

    // phase 0: T0 slice from x -> ring slot 0
    for (int n8 = n0 + w * 8; n8 < n1; n8 += 128) {
        int n = n8 + g;
        if (n < n1) {
            int f = f0 + gl * 8;
            const float* xp = x + ((size_t)(f >> 4) * N_NODES + n) * C_IN + (f & 15);
            float4 u0 = *(const float4*)xp;
            float4 u1 = *(const float4*)(xp + 4);
            float t0v[8] = {u0.x, u0.y, u0.z, u0.w, u1.x, u1.y, u1.z, u1.w};
            *(uint4*)(ring + (size_t)n * F + f) = pack8h(t0v);
        }
    }
    xbar(sync, xcc, nb, 1);

    for (int k = 1; k < K_S; ++k) {
        const u16* sB = ring + (size_t)(k - 1) * RING_ELEMS;
        const u16* sA = ring + (size_t)((k >= 2) ? k - 2 : 0) * RING_ELEMS;
        u16*       dp = ring + (size_t)k * RING_ELEMS;
        const float alpha = (k == 1) ? 1.f : 2.f;
        const bool hasA = (k >= 2);
        const size_t lo2 = (size_t)f0 + (size_t)gl * 8;

        for (int n8 = n0 + w * 8; n8 < n1; n8 += 128) {
            int n = n8 + g;
            if (n >= n1) continue;
            const size_t nlo = (size_t)n * F + lo2;

            float a[8] = {0,0,0,0,0,0,0,0};
            if (hasA) { uint4 ua = *(const uint4*)(sA + nlo); unpack8h(ua, a); }

            int4 m4 = ((const int4*)(epk16 + (size_t)n * 16))[gl];  // entries 2gl,2gl+1
            int plen = row_ptr[n + 1] - row_ptr[n];                 // padded len

            float acc[8] = {0,0,0,0,0,0,0,0};
            {   // round A: entries 0..7
                int cc[8]; float vv[8];
                #pragma unroll
                for (int r = 0; r < 8; ++r) {
                    int src = gbase + (r >> 1);
                    int cx = __shfl((r & 1) ? m4.z : m4.x, src, 64);
                    int vy = __shfl((r & 1) ? m4.w : m4.y, src, 64);
                    cc[r] = cx & 0xFFFF;
                    vv[r] = __int_as_float(vy);
                }
                uint4 q[8];
                #pragma unroll
                for (int r = 0; r < 8; ++r)
                    q[r] = *(const uint4*)(sB + (size_t)cc[r] * F + lo2);
                #pragma unroll
                for (int r = 0; r < 8; ++r) {
                    float b[8];
                    unpack8h(q[r], b);
                    #pragma unroll
                    for (int i = 0; i < 8; ++i) acc[i] += vv[r] * b[i];
                }
            }
            if (plen > 8) {  // round B: entries 8..15
                int cc[8]; float vv[8];
                #pragma unroll
                for (int r = 0; r < 8; ++r) {
                    int src = gbase + 4 + (r >> 1);
                    int cx = __shfl((r & 1) ? m4.z : m4.x, src, 64);
                    int vy = __shfl((r & 1) ? m4.w : m4.y, src, 64);
                    cc[r] = cx & 0xFFFF;
                    vv[r] = __int_as_float(vy);
                }
                uint4 q[8];
                #pragma unroll
                for (int r = 0; r < 8; ++r)
                    q[r] = *(const uint4*)(sB + (size_t)cc[r] * F + lo2);
                #pragma unroll
                for (int r = 0; r < 8; ++r) {
                    float b[8];
                    unpack8h(q[r], b);
                    #pragma unroll
                    for (int i = 0; i < 8; ++i) acc[i] += vv[r] * b[i];
                }
            }
            if (plen > 16) {  // rare overflow: walk sorted cpack from 16
                int s = row_ptr[n];
                for (int base = 16; base < plen; base += 8) {
                    int2 m2 = cpack[s + base + gl];
                    int cc[8]; float vv[8];
                    #pragma unroll
                    for (int r = 0; r < 8; ++r) {
                        cc[r] = __shfl(m2.x, gbase + r, 64) & 0xFFFF;
                        vv[r] = __int_as_float(__shfl(m2.y, gbase + r, 64));
                    }
                    uint4 q[8];
                    #pragma unroll
                    for (int r = 0; r < 8; ++r)
                        q[r] = *(const uint4*)(sB + (size_t)cc[r] * F + lo2);
                    #pragma unroll
                    for (int r = 0; r < 8; ++r) {
                        float b[8];
                        unpack8h(q[r], b);
                        #pragma unroll
                        for (int i = 0; i < 8; ++i) acc[i] += vv[r] * b[i];
                    }
                }
            }

            float y[8];
            #pragma unroll
            for (int i = 0; i < 8; ++i)
                y[i] = alpha * acc[i] - (hasA ? a[i] : 0.f);
            *(uint4*)(dp + nlo) = pack8h(y);
        }
        if (k < K_S - 1) xbar(sync, xcc, nb, k + 1);
    }
    // kernel-end implicit release flushes dirty L2 for proj
}

// ---------------- fallback path kernels (round-8 proven) -------------------

__global__ __launch_bounds__(256) void transform_kernel(
        const float* __restrict__ x, u16* __restrict__ T0) {
    int g = blockIdx.x * 256 + threadIdx.x;
    int n   = g >> 9;
    int rem = g & 511;
    int bt  = rem >> 4;
    int c   = rem & 15;
    float v = x[((size_t)bt * N_NODES + n) * C_IN + c];
    T0[(size_t)n * F + rem] = f2h(v);
}

__global__ __launch_bounds__(256) void spmm16_kernel(
        const u16* __restrict__ srcB, const u16* __restrict__ srcA,
        u16* __restrict__ dst,
        const int2* __restrict__ epk16,
        const int* __restrict__ row_ptr, const int2* __restrict__ cpack,
        float alpha, float beta) {
    const int lane = threadIdx.x & 63;
    const int n = (blockIdx.x << 2) + (threadIdx.x >> 6);
    if (n >= N_NODES) return;

    int2 my = epk16[(size_t)n * 16 + (lane & 15)];
    float a[8] = {0,0,0,0,0,0,0,0};
    if (beta != 0.f) {
        uint4 ua = ((const uint4*)(srcA + (size_t)n * F))[lane];
        unpack8h(ua, a);
    }

    int   c[16]; float v[16];
    #pragma unroll
    for (int r = 0; r < 16; ++r) {
        c[r] = __builtin_amdgcn_readlane(my.x, r) & 0xFFFF;
        v[r] = __int_as_float(__builtin_amdgcn_readlane(my.y, r));
    }

    uint4 g[16];
    #pragma unroll
    for (int r = 0; r < 16; ++r)
        g[r] = ((const uint4*)(srcB + (size_t)c[r] * F))[lane];

    float acc0[8] = {0,0,0,0,0,0,0,0};
    float acc1[8] = {0,0,0,0,0,0,0,0};
    #pragma unroll
    for (int r = 0; r < 16; r += 2) {
        float b0[8], b1[8];
        unpack8h(g[r], b0);
        unpack8h(g[r + 1], b1);
        #pragma unroll
        for (int i = 0; i < 8; ++i) {
            acc0[i] += v[r]     * b0[i];
            acc1[i] += v[r + 1] * b1[i];
        }
    }

    if (__builtin_amdgcn_readlane(my.x, 15) & OVFL_FLAG) {
        int s = row_ptr[n], e_end = row_ptr[n + 1];
        for (int e = s + 16; e < e_end; e += 8) {
            int2 m2 = cpack[e + (lane & 7)];
            #pragma unroll
            for (int r = 0; r < 8; ++r) {
                int   cc = __builtin_amdgcn_readlane(m2.x, r);
                float vv = __int_as_float(__builtin_amdgcn_readlane(m2.y, r));
                uint4 gg = ((const uint4*)(srcB + (size_t)cc * F))[lane];
                float bb[8];
                unpack8h(gg, bb);
                #pragma unroll
                for (int i = 0; i < 8; ++i) acc0[i] += vv * bb[i];
            }
        }
    }

    float y[8];
    #pragma unroll
    for (int i = 0; i < 8; ++i)
        y[i] = alpha * (acc0[i] + acc1[i]) + beta * a[i];

    ((uint4*)(dst + (size_t)n * F))[lane] = pack8h(y);
}

// ---------------- MFMA projection over a chunk (kcnt <= K_S), f16 ----------
// per wave: one node; tile M=32(bt) x N=32(cout), K=kcnt*16.
// A: m=L&31, kk=8*(L>>5)+j ; C/D: col=L&31, row=(reg&3)+8*(reg>>2)+4*(L>>5)

__global__ __launch_bounds__(256) void proj_mfma_kernel(
        const u16* __restrict__ ring, int R, int k0, int kcnt,
        const u16* __restrict__ wtfrag, float* __restrict__ out, int accumulate) {
    const int lane = threadIdx.x & 63;
    const int n = (blockIdx.x << 2) + (threadIdx.x >> 6);
    if (n >= N_NODES) return;
    const int col = lane & 31;
    const int grp = lane >> 5;
    const size_t aoff = (size_t)n * F + (size_t)col * 16 + grp * 8;

    union U { uint4 u; half8 h; };
    float16 acc0 = {};
    float16 acc1 = {};
    int j = 0;
    for (; j + 2 <= kcnt; j += 2) {
        int ka = k0 + j, kb = k0 + j + 1;
        U a0, b0, a1, b1;
        a0.u = *(const uint4*)(ring + (size_t)(ka % R) * RING_ELEMS + aoff);
        b0.u = *(const uint4*)(wtfrag + (size_t)ka * 512 + lane * 8);
        a1.u = *(const uint4*)(ring + (size_t)(kb % R) * RING_ELEMS + aoff);
        b1.u = *(const uint4*)(wtfrag + (size_t)kb * 512 + lane * 8);
        acc0 = __builtin_amdgcn_mfma_f32_32x32x16_f16(a0.h, b0.h, acc0, 0, 0, 0);
        acc1 = __builtin_amdgcn_mfma_f32_32x32x16_f16(a1.h, b1.h, acc1, 0, 0, 0);
    }
    if (j < kcnt) {
        int ka = k0 + j;
        U a0, b0;
        a0.u = *(const uint4*)(ring + (size_t)(ka % R) * RING_ELEMS + aoff);
        b0.u = *(const uint4*)(wtfrag + (size_t)ka * 512 + lane * 8);
        acc0 = __builtin_amdgcn_mfma_f32_32x32x16_f16(a0.h, b0.h, acc0, 0, 0, 0);
    }

    #pragma unroll
    for (int r = 0; r < 16; ++r) {
        int bt = (r & 3) + 8 * (r >> 2) + 4 * grp;
        float* op = out + ((size_t)bt * N_NODES + n) * C_OUT + col;
        float val = acc0[r] + acc1[r];
        if (accumulate) *op += val;
        else            *op  = val;
    }
}

// ---------------- host launch ----------------

extern "C" void kernel_launch(void* const* d_in, const int* in_sizes, int n_in,
                              void* d_out, int out_size, void* d_ws, size_t ws_size,
                              hipStream_t stream) {
    const float* x    = (const float*)d_in[0];
    const int*   erow = (const int*)  d_in[1];
    const int*   ecol = (const int*)  d_in[2];
    const float* eval = (const float*)d_in[3];
    const float* W    = (const float*)d_in[4];
    float* out = (float*)d_out;

    char* ws = (char*)d_ws;
    size_t o = 0;
    auto alloc = [&](size_t bytes) -> char* {
        o = (o + 511) & ~(size_t)511;
        char* r = ws + o;
        o += bytes;
        return r;
    };
    int*   cnt     = (int*)  alloc((size_t)N_NODES * 4);
    int*   row_ptr = (int*)  alloc((size_t)(N_NODES + 1) * 4);
    int*   cursor  = (int*)  alloc((size_t)N_NODES * 4);
    int2*  cpack   = (int2*) alloc((size_t)NNZ_PAD_MAX * 8);
    int2*  epk16   = (int2*) alloc((size_t)N_NODES * 16 * 8);
    u16*   wtfrag  = (u16*)  alloc((size_t)K_S * 512 * 2);
    int*   syncp   = (int*)  alloc(16 * 4);

    o = (o + 511) & ~(size_t)511;
    int R = (int)((ws_size - o) / RING_BYTES);
    if (R > K_S) R = K_S;
    if (R < 3)  R = 3;
    u16* ring = (u16*)(ws + o);
    auto slot = [&](int k) -> u16* { return ring + (size_t)(k % R) * RING_ELEMS; };

    // CSR build: 5 parallel kernels
    init_kernel<<<(N_NODES + K_S * 512 + 255) / 256, 256, 0, stream>>>(W, cnt, wtfrag, syncp);
    count_kernel<<<(NNZ_E + 255) / 256, 256, 0, stream>>>(erow, cnt);
    scan_kernel<<<1, 256, 0, stream>>>(cnt, row_ptr, cursor);
    scatter_kernel<<<(NNZ_E + 255) / 256, 256, 0, stream>>>(erow, ecol, eval, cursor, cpack);
    finalize_kernel<<<(N_NODES + 3) / 4, 256, 0, stream>>>(row_ptr, cursor, cpack, epk16);

    const int grid4 = (N_NODES + 3) / 4;

    if (R >= K_S) {
        // persistent sliced chain: transform + 19 steps, ONE dispatch
        const float* xa = x; const int* rpa = row_ptr; const int2* cpa = cpack;
        const int2* eka = epk16; u16* ra = ring; int* sy = syncp;
        void* args[] = {(void*)&xa, (void*)&rpa, (void*)&cpa,
                        (void*)&eka, (void*)&ra, (void*)&sy};
        hipError_t err = hipLaunchCooperativeKernel(
            (const void*)chain_bsp_kernel, dim3(256), dim3(1024), args, 0, stream);
        if (err == hipSuccess) {
            proj_mfma_kernel<<<grid4, 256, 0, stream>>>(
                ring, K_S, 0, K_S, wtfrag, out, 0);
            return;
        }
        (void)hipGetLastError();  // clear; fall through to multi-launch path
    }

    // fallback: round-8 multi-launch pipeline
    int c0 = 0;
    auto maybe_pass = [&](int k_done) {
        int target = K_S - c0;
        if (target > R) target = R;
        if (target > 0 && (k_done - c0 + 1) == target) {
            proj_mfma_kernel<<<grid4, 256, 0, stream>>>(
                ring, R, c0, target, wtfrag, out, (c0 > 0) ? 1 : 0);
            c0 += target;
        }
    };

    transform_kernel<<<(int)(RING_ELEMS / 256), 256, 0, stream>>>(x, slot(0));
    maybe_pass(0);
    for (int k = 1; k < K_S; ++k) {
        const u16* srcB = slot(k - 1);
        const u16* srcA = (k >= 2) ? slot(k - 2) : slot(k - 1);
        float alpha = (k == 1) ? 1.f : 2.f;
        float beta  = (k == 1) ? 0.f : -1.f;
        spmm16_kernel<<<grid4, 256, 0, stream>>>(
            srcB, srcA, slot(k), epk16, row_ptr, cpack, alpha, beta);
        maybe_pass(k);
    }
}

// Round 11
// 496.162 us; speedup vs baseline: 1.0173x; 1.0173x over previous
//
#include <hip/hip_runtime.h>
#include <hip/hip_cooperative_groups.h>

namespace cg = cooperative_groups;

#define N_NODES 10242
#define NNZ_E   71694
// rows padded to multiple of 8, +64 slack for cooperative over-read
#define NNZ_PAD_MAX (NNZ_E + 7 * N_NODES + 64)
#define BT      32      // B*T
#define C_IN    16
#define K_S     20
#define C_OUT   32
#define F       512     // BT * C_IN
typedef unsigned short u16;
typedef unsigned int   u32;
typedef unsigned long long u64;

#define RING_ELEMS ((size_t)N_NODES * F)    // f16 elems per ring slot, layout [n][bt*16+c]
#define RING_BYTES (RING_ELEMS * 2)         // ~10.5 MB

#define OVFL_FLAG (1 << 30)
#define CAP 336          // max nodes per block held in LDS (nb>=31 fits)

typedef __attribute__((ext_vector_type(8)))  _Float16 half8;
typedef __attribute__((ext_vector_type(16))) float    float16;

__device__ __forceinline__ void unpack8h(uint4 u, float* f) {
    union { uint4 u; _Float16 h[8]; } v; v.u = u;
    #pragma unroll
    for (int i = 0; i < 8; ++i) f[i] = (float)v.h[i];
}
__device__ __forceinline__ uint4 pack8h(const float* f) {
    union { uint4 u; _Float16 h[8]; } v;
    #pragma unroll
    for (int i = 0; i < 8; ++i) v.h[i] = (_Float16)f[i];
    return v.u;
}
__device__ __forceinline__ u16 f2h(float f) {
    union { _Float16 h; u16 u; } v; v.h = (_Float16)f; return v.u;
}

// ---------------- parallel CSR build (5 small wide-grid kernels) -----------
// Determinism: per-row (col,valbits) multiset is fixed; rank-sort by
// (col,valbits,pos) makes the CSR (and f32 accumulation order) deterministic.
// Rows padded to x8 with (col=0,val=0) entries (contribute exactly 0).

__global__ __launch_bounds__(256) void init_kernel(
        const float* __restrict__ W, int* __restrict__ cnt,
        u16* __restrict__ wtfrag, int* __restrict__ syncp) {
    int i = blockIdx.x * 256 + threadIdx.x;
    if (i < N_NODES) cnt[i] = 0;
    if (i < 16) syncp[i] = 0;
    int w = i - N_NODES;
    if (w >= 0 && w < K_S * 64 * 8) {
        // B-frag for v_mfma_f32_32x32x16_f16: lane L, reg j ->
        // B[k=8*(L>>5)+j][col=L&31] = W[cout=col][c=k][k_cheb]
        int j    = w & 7;
        int lane = (w >> 3) & 63;
        int k    = w >> 9;
        int cout = lane & 31;
        int c    = ((lane >> 5) << 3) + j;
        wtfrag[w] = f2h(W[cout * (C_IN * K_S) + c * K_S + k]);
    }
}

__global__ __launch_bounds__(256) void count_kernel(
        const int* __restrict__ erow, int* cnt) {
    int e = blockIdx.x * 256 + threadIdx.x;
    if (e < NNZ_E) atomicAdd(&cnt[erow[e]], 1);
}

__global__ __launch_bounds__(256) void scan_kernel(
        const int* __restrict__ cnt, int* row_ptr, int* cursor) {
    const int T = 256;
    const int chunk = (N_NODES + T - 1) / T;  // 41
    __shared__ int part[T];
    int t = threadIdx.x;
    int base = t * chunk;
    int s = 0;
    for (int i = 0; i < chunk; ++i) {
        int idx = base + i;
        if (idx < N_NODES) s += (cnt[idx] + 7) & ~7;
    }
    part[t] = s;
    __syncthreads();
    for (int off = 1; off < T; off <<= 1) {
        int v = (t >= off) ? part[t - off] : 0;
        __syncthreads();
        part[t] += v;
        __syncthreads();
    }
    int run = (t == 0) ? 0 : part[t - 1];
    for (int i = 0; i < chunk; ++i) {
        int idx = base + i;
        if (idx < N_NODES) {
            row_ptr[idx] = run;
            cursor[idx]  = run;
            run += (cnt[idx] + 7) & ~7;
        }
    }
    if (t == T - 1) row_ptr[N_NODES] = part[T - 1];
}

__global__ __launch_bounds__(256) void scatter_kernel(
        const int* __restrict__ erow, const int* __restrict__ ecol,
        const float* __restrict__ eval, int* cursor, int2* __restrict__ cpack) {
    int e = blockIdx.x * 256 + threadIdx.x;
    if (e < NNZ_E) {
        int p = atomicAdd(&cursor[erow[e]], 1);
        cpack[p] = make_int2(ecol[e], __float_as_int(eval[e]));
    }
}

// wave-per-row rank sort + pad + fixed-16 pack (round-8 proven)
__global__ __launch_bounds__(256) void finalize_kernel(
        const int* __restrict__ row_ptr, const int* __restrict__ cursor,
        int2* cpack, int2* __restrict__ epk16) {
    const int lane = threadIdx.x & 63;
    const int r = (blockIdx.x << 2) + (threadIdx.x >> 6);
    if (r >= N_NODES) return;
    const int sbeg = row_ptr[r];
    const int send = cursor[r];      // sbeg + real count
    const int pend = row_ptr[r + 1]; // sbeg + padded count
    const int rlen = send - sbeg;
    const int plen = pend - sbeg;

    if (plen > 64) {                 // essentially impossible; serial fallback
        if (lane == 0) {
            for (int i = sbeg + 1; i < send; ++i) {
                int2 key = cpack[i];
                int j = i - 1;
                while (j >= sbeg) {
                    int2 q = cpack[j];
                    bool gt = (q.x > key.x) || (q.x == key.x && (u32)q.y > (u32)key.y);
                    if (!gt) break;
                    cpack[j + 1] = q; --j;
                }
                cpack[j + 1] = key;
            }
            for (int p = send; p < pend; ++p) cpack[p] = make_int2(0, 0);
            for (int p = 0; p < 16; ++p) {
                int2 v = (p < plen) ? cpack[sbeg + p] : make_int2(0, 0);
                if (p == 15 && rlen > 16) v.x |= OVFL_FLAG;
                epk16[(size_t)r * 16 + p] = v;
            }
        }
        return;
    }

    const bool real = (lane < rlen);
    int2 e = real ? cpack[sbeg + lane] : make_int2(0, 0);
    const u64 ki = ((u64)(u32)e.x << 32) | (u32)e.y;

    int rank = 0;
    for (int j = 0; j < rlen; ++j) {
        int cx = __shfl(e.x, j, 64);
        int cy = __shfl(e.y, j, 64);
        u64 kj = ((u64)(u32)cx << 32) | (u32)cy;
        if (kj < ki || (kj == ki && j < lane)) ++rank;
    }
    if (!real) rank = lane;

    if (lane < plen) cpack[sbeg + rank] = real ? e : make_int2(0, 0);

    int2 v16 = real ? e : make_int2(0, 0);
    if (rank == 15 && rlen > 16) v16.x |= OVFL_FLAG;
    if (rank < 16) epk16[(size_t)r * 16 + rank] = v16;
}

// ---------------- per-XCD BSP barrier --------------------------------------
// Monotonic counter; RELAXED atomics only. Producer stores drained to L2 by
// the explicit vmcnt(0) before the counter increment; consumers' plain loads
// then read current L2 data (slice-private, write-once slots -> no stale L1).

__device__ __forceinline__ void xbar(int* sync, int xcc, int nb, int target_mult) {
    asm volatile("s_waitcnt vmcnt(0)" ::: "memory");
    __syncthreads();
    if (threadIdx.x == 0) {
        __hip_atomic_fetch_add(&sync[8 + xcc], 1, __ATOMIC_RELAXED,
                               __HIP_MEMORY_SCOPE_AGENT);
        const int tgt = target_mult * nb;
        while (__hip_atomic_load(&sync[8 + xcc], __ATOMIC_RELAXED,
                                 __HIP_MEMORY_SCOPE_AGENT) < tgt)
            __builtin_amdgcn_s_sleep(16);
    }
    __syncthreads();
    asm volatile("" ::: "memory");
}

// ---------------- persistent sliced Chebyshev chain (cooperative) ----------
// XCD j owns column slice j. Round-10 PMC showed the 5.2MB/XCD working set
// (srcB+srcA+dst+epk16) thrashes the 4MB L2 -> whole ring round-trips HBM.
// Fix: block-PRIVATE state moves to LDS — srcA parity mirror ldsT[k&1]
// (own nodes' slot k-2, computed by this block 2 steps ago), epk16 rows,
// plen. L2 then holds only srcB gathered slice + dst write-allocate
// (~2.6MB < 4MB) -> gathers hit L2. Node stride padded to 144B (9 uint4)
// for conflict-free ds_read_b128. ~146KB LDS also forces 1 block/CU.

__global__ __launch_bounds__(1024) void chain_bsp_kernel(
        const float* __restrict__ x,
        const int* __restrict__ row_ptr, const int2* __restrict__ cpack,
        const int2* __restrict__ epk16,
        u16* __restrict__ ring, int* __restrict__ sync) {
    __shared__ int   shv[2];
    __shared__ uint4 ldsT[2][CAP * 9];   // T slices, parity by k&1; stride 9
    __shared__ int4  ldsE[CAP * 9];      // epk16 rows (8 int4/node); stride 9
    __shared__ int   ldsP[CAP];          // padded row lengths
    cg::grid_group grid = cg::this_grid();

    if (threadIdx.x == 0) {
        // HW_REG_XCC_ID (id=20), offset 0, size 32
        int xcc = __builtin_amdgcn_s_getreg((31 << 11) | (0 << 6) | 20) & 7;
        shv[0] = xcc;
        shv[1] = atomicAdd(&sync[xcc], 1);   // rank within this XCD
    }
    __syncthreads();
    const int xcc  = shv[0];
    const int rank = shv[1];
    grid.sync();                              // registration complete
    const int nb = sync[xcc];                 // blocks on this XCD

    const int w     = threadIdx.x >> 6;
    const int l     = threadIdx.x & 63;
    const int g     = l >> 3;
    const int gl    = l & 7;
    const int gbase = l & 56;
    const int f0    = xcc << 6;               // 64-col slice base

    const int chunk = (N_NODES + nb - 1) / nb;
    const int n0 = rank * chunk;
    int n1 = n0 + chunk; if (n1 > N_NODES) n1 = N_NODES;
    const int nlocal = n1 - n0;
    const bool fits = (nlocal <= CAP);        // nb>=31 -> always true

    // preload block-private epk16 rows + plen into LDS
    if (fits) {
        for (int i = threadIdx.x; i < nlocal * 8; i += 1024) {
            int ln = i >> 3, j = i & 7;
            ldsE[ln * 9 + j] = ((const int4*)(epk16 + (size_t)(n0 + ln) * 16))[j];
        }
        for (int i = threadIdx.x; i < nlocal; i += 1024)
            ldsP[i] = row_ptr[n0 + i + 1] - row_ptr[n0 + i];
    }
    __syncthreads();

    // phase 0: T0 slice from x -> ring slot 0 (+ LDS parity 0)
    for (int n8 = n0 + w * 8; n8 < n1; n8 += 128) {
        int n = n8 + g;
        if (n < n1) {
            int f = f0 + gl * 8;
            const float* xp = x + ((size_t)(f >> 4) * N_NODES + n) * C_IN + (f & 15);
            float4 u0 = *(const float4*)xp;
            float4 u1 = *(const float4*)(xp + 4);
            float t0v[8] = {u0.x, u0.y, u0.z, u0.w, u1.x, u1.y, u1.z, u1.w};
            uint4 p = pack8h(t0v);
            *(uint4*)(ring + (size_t)n * F + f) = p;
            if (fits) ldsT[0][(n - n0) * 9 + gl] = p;
        }
    }
    xbar(sync, xcc, nb, 1);

    for (int k = 1; k < K_S; ++k) {
        const u16* sB = ring + (size_t)(k - 1) * RING_ELEMS;
        const u16* sA = ring + (size_t)((k >= 2) ? k - 2 : 0) * RING_ELEMS;
        u16*       dp = ring + (size_t)k * RING_ELEMS;
        const float alpha = (k == 1) ? 1.f : 2.f;
        const bool hasA = (k >= 2);
        const int par = k & 1;                // slot k lives at ldsT[par]; k-2 too
        const size_t lo2 = (size_t)f0 + (size_t)gl * 8;

        for (int n8 = n0 + w * 8; n8 < n1; n8 += 128) {
            int n = n8 + g;
            if (n >= n1) continue;
            const int ln = n - n0;
            const size_t nlo = (size_t)n * F + lo2;

            float a[8] = {0,0,0,0,0,0,0,0};
            if (hasA) {
                uint4 ua = fits ? ldsT[par][ln * 9 + gl]
                                : *(const uint4*)(sA + nlo);
                unpack8h(ua, a);
            }

            int4 m4 = fits ? ldsE[ln * 9 + gl]
                           : ((const int4*)(epk16 + (size_t)n * 16))[gl];
            int plen = fits ? ldsP[ln] : (row_ptr[n + 1] - row_ptr[n]);

            float acc[8] = {0,0,0,0,0,0,0,0};
            {   // round A: entries 0..7
                int cc[8]; float vv[8];
                #pragma unroll
                for (int r = 0; r < 8; ++r) {
                    int src = gbase + (r >> 1);
                    int cx = __shfl((r & 1) ? m4.z : m4.x, src, 64);
                    int vy = __shfl((r & 1) ? m4.w : m4.y, src, 64);
                    cc[r] = cx & 0xFFFF;
                    vv[r] = __int_as_float(vy);
                }
                uint4 q[8];
                #pragma unroll
                for (int r = 0; r < 8; ++r)
                    q[r] = *(const uint4*)(sB + (size_t)cc[r] * F + lo2);
                #pragma unroll
                for (int r = 0; r < 8; ++r) {
                    float b[8];
                    unpack8h(q[r], b);
                    #pragma unroll
                    for (int i = 0; i < 8; ++i) acc[i] += vv[r] * b[i];
                }
            }
            if (plen > 8) {  // round B: entries 8..15
                int cc[8]; float vv[8];
                #pragma unroll
                for (int r = 0; r < 8; ++r) {
                    int src = gbase + 4 + (r >> 1);
                    int cx = __shfl((r & 1) ? m4.z : m4.x, src, 64);
                    int vy = __shfl((r & 1) ? m4.w : m4.y, src, 64);
                    cc[r] = cx & 0xFFFF;
                    vv[r] = __int_as_float(vy);
                }
                uint4 q[8];
                #pragma unroll
                for (int r = 0; r < 8; ++r)
                    q[r] = *(const uint4*)(sB + (size_t)cc[r] * F + lo2);
                #pragma unroll
                for (int r = 0; r < 8; ++r) {
                    float b[8];
                    unpack8h(q[r], b);
                    #pragma unroll
                    for (int i = 0; i < 8; ++i) acc[i] += vv[r] * b[i];
                }
            }
            if (plen > 16) {  // rare overflow: walk sorted cpack from 16
                int s = row_ptr[n];
                for (int base = 16; base < plen; base += 8) {
                    int2 m2 = cpack[s + base + gl];
                    int cc[8]; float vv[8];
                    #pragma unroll
                    for (int r = 0; r < 8; ++r) {
                        cc[r] = __shfl(m2.x, gbase + r, 64) & 0xFFFF;
                        vv[r] = __int_as_float(__shfl(m2.y, gbase + r, 64));
                    }
                    uint4 q[8];
                    #pragma unroll
                    for (int r = 0; r < 8; ++r)
                        q[r] = *(const uint4*)(sB + (size_t)cc[r] * F + lo2);
                    #pragma unroll
                    for (int r = 0; r < 8; ++r) {
                        float b[8];
                        unpack8h(q[r], b);
                        #pragma unroll
                        for (int i = 0; i < 8; ++i) acc[i] += vv[r] * b[i];
                    }
                }
            }

            float y[8];
            #pragma unroll
            for (int i = 0; i < 8; ++i)
                y[i] = alpha * acc[i] - (hasA ? a[i] : 0.f);
            uint4 yp = pack8h(y);
            *(uint4*)(dp + nlo) = yp;
            if (fits) ldsT[par][ln * 9 + gl] = yp;   // read-then-overwrite, same thread
        }
        if (k < K_S - 1) xbar(sync, xcc, nb, k + 1);
    }
    // kernel-end implicit release flushes dirty L2 for proj
}

// ---------------- fallback path kernels (round-8 proven) -------------------

__global__ __launch_bounds__(256) void transform_kernel(
        const float* __restrict__ x, u16* __restrict__ T0) {
    int g = blockIdx.x * 256 + threadIdx.x;
    int n   = g >> 9;
    int rem = g & 511;
    int bt  = rem >> 4;
    int c   = rem & 15;
    float v = x[((size_t)bt * N_NODES + n) * C_IN + c];
    T0[(size_t)n * F + rem] = f2h(v);
}

__global__ __launch_bounds__(256) void spmm16_kernel(
        const u16* __restrict__ srcB, const u16* __restrict__ srcA,
        u16* __restrict__ dst,
        const int2* __restrict__ epk16,
        const int* __restrict__ row_ptr, const int2* __restrict__ cpack,
        float alpha, float beta) {
    const int lane = threadIdx.x & 63;
    const int n = (blockIdx.x << 2) + (threadIdx.x >> 6);
    if (n >= N_NODES) return;

    int2 my = epk16[(size_t)n * 16 + (lane & 15)];
    float a[8] = {0,0,0,0,0,0,0,0};
    if (beta != 0.f) {
        uint4 ua = ((const uint4*)(srcA + (size_t)n * F))[lane];
        unpack8h(ua, a);
    }

    int   c[16]; float v[16];
    #pragma unroll
    for (int r = 0; r < 16; ++r) {
        c[r] = __builtin_amdgcn_readlane(my.x, r) & 0xFFFF;
        v[r] = __int_as_float(__builtin_amdgcn_readlane(my.y, r));
    }

    uint4 g[16];
    #pragma unroll
    for (int r = 0; r < 16; ++r)
        g[r] = ((const uint4*)(srcB + (size_t)c[r] * F))[lane];

    float acc0[8] = {0,0,0,0,0,0,0,0};
    float acc1[8] = {0,0,0,0,0,0,0,0};
    #pragma unroll
    for (int r = 0; r < 16; r += 2) {
        float b0[8], b1[8];
        unpack8h(g[r], b0);
        unpack8h(g[r + 1], b1);
        #pragma unroll
        for (int i = 0; i < 8; ++i) {
            acc0[i] += v[r]     * b0[i];
            acc1[i] += v[r + 1] * b1[i];
        }
    }

    if (__builtin_amdgcn_readlane(my.x, 15) & OVFL_FLAG) {
        int s = row_ptr[n], e_end = row_ptr[n + 1];
        for (int e = s + 16; e < e_end; e += 8) {
            int2 m2 = cpack[e + (lane & 7)];
            #pragma unroll
            for (int r = 0; r < 8; ++r) {
                int   cc = __builtin_amdgcn_readlane(m2.x, r);
                float vv = __int_as_float(__builtin_amdgcn_readlane(m2.y, r));
                uint4 gg = ((const uint4*)(srcB + (size_t)cc * F))[lane];
                float bb[8];
                unpack8h(gg, bb);
                #pragma unroll
                for (int i = 0; i < 8; ++i) acc0[i] += vv * bb[i];
            }
        }
    }

    float y[8];
    #pragma unroll
    for (int i = 0; i < 8; ++i)
        y[i] = alpha * (acc0[i] + acc1[i]) + beta * a[i];

    ((uint4*)(dst + (size_t)n * F))[lane] = pack8h(y);
}

// ---------------- MFMA projection over a chunk (kcnt <= K_S), f16 ----------
// per wave: one node; tile M=32(bt) x N=32(cout), K=kcnt*16.
// A: m=L&31, kk=8*(L>>5)+j ; C/D: col=L&31, row=(reg&3)+8*(reg>>2)+4*(L>>5)

__global__ __launch_bounds__(256) void proj_mfma_kernel(
        const u16* __restrict__ ring, int R, int k0, int kcnt,
        const u16* __restrict__ wtfrag, float* __restrict__ out, int accumulate) {
    const int lane = threadIdx.x & 63;
    const int n = (blockIdx.x << 2) + (threadIdx.x >> 6);
    if (n >= N_NODES) return;
    const int col = lane & 31;
    const int grp = lane >> 5;
    const size_t aoff = (size_t)n * F + (size_t)col * 16 + grp * 8;

    union U { uint4 u; half8 h; };
    float16 acc0 = {};
    float16 acc1 = {};
    int j = 0;
    for (; j + 2 <= kcnt; j += 2) {
        int ka = k0 + j, kb = k0 + j + 1;
        U a0, b0, a1, b1;
        a0.u = *(const uint4*)(ring + (size_t)(ka % R) * RING_ELEMS + aoff);
        b0.u = *(const uint4*)(wtfrag + (size_t)ka * 512 + lane * 8);
        a1.u = *(const uint4*)(ring + (size_t)(kb % R) * RING_ELEMS + aoff);
        b1.u = *(const uint4*)(wtfrag + (size_t)kb * 512 + lane * 8);
        acc0 = __builtin_amdgcn_mfma_f32_32x32x16_f16(a0.h, b0.h, acc0, 0, 0, 0);
        acc1 = __builtin_amdgcn_mfma_f32_32x32x16_f16(a1.h, b1.h, acc1, 0, 0, 0);
    }
    if (j < kcnt) {
        int ka = k0 + j;
        U a0, b0;
        a0.u = *(const uint4*)(ring + (size_t)(ka % R) * RING_ELEMS + aoff);
        b0.u = *(const uint4*)(wtfrag + (size_t)ka * 512 + lane * 8);
        acc0 = __builtin_amdgcn_mfma_f32_32x32x16_f16(a0.h, b0.h, acc0, 0, 0, 0);
    }

    #pragma unroll
    for (int r = 0; r < 16; ++r) {
        int bt = (r & 3) + 8 * (r >> 2) + 4 * grp;
        float* op = out + ((size_t)bt * N_NODES + n) * C_OUT + col;
        float val = acc0[r] + acc1[r];
        if (accumulate) *op += val;
        else            *op  = val;
    }
}

// ---------------- host launch ----------------

extern "C" void kernel_launch(void* const* d_in, const int* in_sizes, int n_in,
                              void* d_out, int out_size, void* d_ws, size_t ws_size,
                              hipStream_t stream) {
    const float* x    = (const float*)d_in[0];
    const int*   erow = (const int*)  d_in[1];
    const int*   ecol = (const int*)  d_in[2];
    const float* eval = (const float*)d_in[3];
    const float* W    = (const float*)d_in[4];
    float* out = (float*)d_out;

    char* ws = (char*)d_ws;
    size_t o = 0;
    auto alloc = [&](size_t bytes) -> char* {
        o = (o + 511) & ~(size_t)511;
        char* r = ws + o;
        o += bytes;
        return r;
    };
    int*   cnt     = (int*)  alloc((size_t)N_NODES * 4);
    int*   row_ptr = (int*)  alloc((size_t)(N_NODES + 1) * 4);
    int*   cursor  = (int*)  alloc((size_t)N_NODES * 4);
    int2*  cpack   = (int2*) alloc((size_t)NNZ_PAD_MAX * 8);
    int2*  epk16   = (int2*) alloc((size_t)N_NODES * 16 * 8);
    u16*   wtfrag  = (u16*)  alloc((size_t)K_S * 512 * 2);
    int*   syncp   = (int*)  alloc(16 * 4);

    o = (o + 511) & ~(size_t)511;
    int R = (int)((ws_size - o) / RING_BYTES);
    if (R > K_S) R = K_S;
    if (R < 3)  R = 3;
    u16* ring = (u16*)(ws + o);
    auto slot = [&](int k) -> u16* { return ring + (size_t)(k % R) * RING_ELEMS; };

    // CSR build: 5 parallel kernels
    init_kernel<<<(N_NODES + K_S * 512 + 255) / 256, 256, 0, stream>>>(W, cnt, wtfrag, syncp);
    count_kernel<<<(NNZ_E + 255) / 256, 256, 0, stream>>>(erow, cnt);
    scan_kernel<<<1, 256, 0, stream>>>(cnt, row_ptr, cursor);
    scatter_kernel<<<(NNZ_E + 255) / 256, 256, 0, stream>>>(erow, ecol, eval, cursor, cpack);
    finalize_kernel<<<(N_NODES + 3) / 4, 256, 0, stream>>>(row_ptr, cursor, cpack, epk16);

    const int grid4 = (N_NODES + 3) / 4;

    if (R >= K_S) {
        // persistent sliced chain: transform + 19 steps, ONE dispatch
        const float* xa = x; const int* rpa = row_ptr; const int2* cpa = cpack;
        const int2* eka = epk16; u16* ra = ring; int* sy = syncp;
        void* args[] = {(void*)&xa, (void*)&rpa, (void*)&cpa,
                        (void*)&eka, (void*)&ra, (void*)&sy};
        hipError_t err = hipLaunchCooperativeKernel(
            (const void*)chain_bsp_kernel, dim3(256), dim3(1024), args, 0, stream);
        if (err == hipSuccess) {
            proj_mfma_kernel<<<grid4, 256, 0, stream>>>(
                ring, K_S, 0, K_S, wtfrag, out, 0);
            return;
        }
        (void)hipGetLastError();  // clear; fall through to multi-launch path
    }

    // fallback: round-8 multi-launch pipeline
    int c0 = 0;
    auto maybe_pass = [&](int k_done) {
        int target = K_S - c0;
        if (target > R) target = R;
        if (target > 0 && (k_done - c0 + 1) == target) {
            proj_mfma_kernel<<<grid4, 256, 0, stream>>>(
                ring, R, c0, target, wtfrag, out, (c0 > 0) ? 1 : 0);
            c0 += target;
        }
    };

    transform_kernel<<<(int)(RING_ELEMS / 256), 256, 0, stream>>>(x, slot(0));
    maybe_pass(0);
    for (int k = 1; k < K_S; ++k) {
        const u16* srcB = slot(k - 1);
        const u16* srcA = (k >= 2) ? slot(k - 2) : slot(k - 1);
        float alpha = (k == 1) ? 1.f : 2.f;
        float beta  = (k == 1) ? 0.f : -1.f;
        spmm16_kernel<<<grid4, 256, 0, stream>>>(
            srcB, srcA, slot(k), epk16, row_ptr, cpack, alpha, beta);
        maybe_pass(k);
    }
}

// Round 13
// 411.703 us; speedup vs baseline: 1.2260x; 1.2051x over previous
//
#include <hip/hip_runtime.h>

#define N_NODES 10242
#define NNZ_E   71694
// rows padded to multiple of 8, +64 slack for cooperative over-read
#define NNZ_PAD_MAX (NNZ_E + 7 * N_NODES + 64)
#define BT      32      // B*T
#define C_IN    16
#define K_S     20
#define C_OUT   32
#define F       512     // BT * C_IN
typedef unsigned short u16;
typedef unsigned int   u32;
typedef unsigned long long u64;

#define RING_ELEMS ((size_t)N_NODES * F)    // f16 elems per ring slot, layout [n][bt*16+c]
#define RING_BYTES (RING_ELEMS * 2)         // ~10.5 MB

#define OVFL_FLAG (1 << 30)

typedef __attribute__((ext_vector_type(8)))  _Float16 half8;
typedef __attribute__((ext_vector_type(16))) float    float16;

__device__ __forceinline__ void unpack8h(uint4 u, float* f) {
    union { uint4 u; _Float16 h[8]; } v; v.u = u;
    #pragma unroll
    for (int i = 0; i < 8; ++i) f[i] = (float)v.h[i];
}
__device__ __forceinline__ uint4 pack8h(const float* f) {
    union { uint4 u; _Float16 h[8]; } v;
    #pragma unroll
    for (int i = 0; i < 8; ++i) v.h[i] = (_Float16)f[i];
    return v.u;
}
__device__ __forceinline__ u16 f2h(float f) {
    union { _Float16 h; u16 u; } v; v.h = (_Float16)f; return v.u;
}

// ---------------- parallel CSR build (5 small wide-grid kernels) -----------
// Determinism: per-row (col,valbits) multiset is fixed; rank-sort by
// (col,valbits,pos) makes the CSR (and f32 accumulation order) deterministic.
// Rows padded to x8 with (col=0,val=0) entries (contribute exactly 0).
// finalize also emits the FIXED-STRIDE 16-entry table epk16[n] and writes
// the T0 slice (transform folded in — same wave-per-node grid, independent
// work; saves one dispatch).

__global__ __launch_bounds__(256) void init_kernel(
        const float* __restrict__ W, int* __restrict__ cnt,
        u16* __restrict__ wtfrag) {
    int i = blockIdx.x * 256 + threadIdx.x;
    if (i < N_NODES) cnt[i] = 0;
    int w = i - N_NODES;
    if (w >= 0 && w < K_S * 64 * 8) {
        // B-frag for v_mfma_f32_32x32x16_f16: lane L, reg j ->
        // B[k=8*(L>>5)+j][col=L&31] = W[cout=col][c=k][k_cheb]
        int j    = w & 7;
        int lane = (w >> 3) & 63;
        int k    = w >> 9;
        int cout = lane & 31;
        int c    = ((lane >> 5) << 3) + j;
        wtfrag[w] = f2h(W[cout * (C_IN * K_S) + c * K_S + k]);
    }
}

__global__ __launch_bounds__(256) void count_kernel(
        const int* __restrict__ erow, int* cnt) {
    int e = blockIdx.x * 256 + threadIdx.x;
    if (e < NNZ_E) atomicAdd(&cnt[erow[e]], 1);
}

__global__ __launch_bounds__(256) void scan_kernel(
        const int* __restrict__ cnt, int* row_ptr, int* cursor) {
    const int T = 256;
    const int chunk = (N_NODES + T - 1) / T;  // 41
    __shared__ int part[T];
    int t = threadIdx.x;
    int base = t * chunk;
    int s = 0;
    for (int i = 0; i < chunk; ++i) {
        int idx = base + i;
        if (idx < N_NODES) s += (cnt[idx] + 7) & ~7;
    }
    part[t] = s;
    __syncthreads();
    for (int off = 1; off < T; off <<= 1) {
        int v = (t >= off) ? part[t - off] : 0;
        __syncthreads();
        part[t] += v;
        __syncthreads();
    }
    int run = (t == 0) ? 0 : part[t - 1];
    for (int i = 0; i < chunk; ++i) {
        int idx = base + i;
        if (idx < N_NODES) {
            row_ptr[idx] = run;
            cursor[idx]  = run;
            run += (cnt[idx] + 7) & ~7;
        }
    }
    if (t == T - 1) row_ptr[N_NODES] = part[T - 1];
}

__global__ __launch_bounds__(256) void scatter_kernel(
        const int* __restrict__ erow, const int* __restrict__ ecol,
        const float* __restrict__ eval, int* cursor, int2* __restrict__ cpack) {
    int e = blockIdx.x * 256 + threadIdx.x;
    if (e < NNZ_E) {
        int p = atomicAdd(&cursor[erow[e]], 1);
        cpack[p] = make_int2(ecol[e], __float_as_int(eval[e]));
    }
}

// wave-per-row: RANK SORT + pad + fixed-16 pack + T0-slice write (transform).
// All lanes run the uniform shfl broadcast loop; rank = #{keys < mine} with
// (col,valbits,pos) tie-break (strict total order -> bijection over lanes).
__global__ __launch_bounds__(256) void finalize_kernel(
        const int* __restrict__ row_ptr, const int* __restrict__ cursor,
        int2* cpack, int2* __restrict__ epk16,
        const float* __restrict__ x, u16* __restrict__ T0) {
    const int lane = threadIdx.x & 63;
    const int r = (blockIdx.x << 2) + (threadIdx.x >> 6);
    if (r >= N_NODES) return;

    // --- transform: own T0 row (independent of the sort) ---
    {
        const int bt = lane >> 1;
        const int hc = (lane & 1) * 8;
        const float* xp = x + ((size_t)bt * N_NODES + r) * C_IN + hc;
        float4 u0 = *(const float4*)xp;
        float4 u1 = *(const float4*)(xp + 4);
        float t0v[8] = {u0.x, u0.y, u0.z, u0.w, u1.x, u1.y, u1.z, u1.w};
        ((uint4*)(T0 + (size_t)r * F))[lane] = pack8h(t0v);
    }

    const int sbeg = row_ptr[r];
    const int send = cursor[r];      // sbeg + real count
    const int pend = row_ptr[r + 1]; // sbeg + padded count
    const int rlen = send - sbeg;
    const int plen = pend - sbeg;

    if (plen > 64) {                 // essentially impossible; serial fallback
        if (lane == 0) {
            for (int i = sbeg + 1; i < send; ++i) {
                int2 key = cpack[i];
                int j = i - 1;
                while (j >= sbeg) {
                    int2 q = cpack[j];
                    bool gt = (q.x > key.x) || (q.x == key.x && (u32)q.y > (u32)key.y);
                    if (!gt) break;
                    cpack[j + 1] = q; --j;
                }
                cpack[j + 1] = key;
            }
            for (int p = send; p < pend; ++p) cpack[p] = make_int2(0, 0);
            for (int p = 0; p < 16; ++p) {
                int2 v = (p < plen) ? cpack[sbeg + p] : make_int2(0, 0);
                if (p == 15 && rlen > 16) v.x |= OVFL_FLAG;
                epk16[(size_t)r * 16 + p] = v;
            }
        }
        return;
    }

    const bool real = (lane < rlen);
    int2 e = real ? cpack[sbeg + lane] : make_int2(0, 0);
    const u64 ki = ((u64)(u32)e.x << 32) | (u32)e.y;

    int rank = 0;
    for (int j = 0; j < rlen; ++j) {      // wave-uniform bound
        int cx = __shfl(e.x, j, 64);
        int cy = __shfl(e.y, j, 64);
        u64 kj = ((u64)(u32)cx << 32) | (u32)cy;
        if (kj < ki || (kj == ki && j < lane)) ++rank;
    }
    if (!real) rank = lane;               // pads/idle keep own position

    // sorted cpack: reals at [0,rlen), zero pads at [rlen,plen)
    if (lane < plen) cpack[sbeg + rank] = real ? e : make_int2(0, 0);

    // epk16 direct from ranks (positions 0..15 covered bijectively)
    int2 v16 = real ? e : make_int2(0, 0);
    if (rank == 15 && rlen > 16) v16.x |= OVFL_FLAG;
    if (rank < 16) epk16[(size_t)r * 16 + rank] = v16;
}

// ---------------- Chebyshev step: wave-per-node, fixed-16 burst ------------
// dst = alpha * L @ srcB + beta * srcA.
// Two memory rounds only: {epk16 row (address = n*16, no row_ptr dep), srcA}
// issued together, then ONE unrolled burst of 16 gathers. Pad entries are
// (col=0, val=0): their gathers hit node 0's row (always cache-hot) and
// contribute exactly 0. Rows with >16 real edges (rare) take the flagged
// overflow path through the original CSR.

__global__ __launch_bounds__(256) void spmm16_kernel(
        const u16* __restrict__ srcB, const u16* __restrict__ srcA,
        u16* __restrict__ dst,
        const int2* __restrict__ epk16,
        const int* __restrict__ row_ptr, const int2* __restrict__ cpack,
        float alpha, float beta) {
    const int lane = threadIdx.x & 63;
    const int n = (blockIdx.x << 2) + (threadIdx.x >> 6);
    if (n >= N_NODES) return;

    // round 1: edge slot (known address) + srcA, independent
    int2 my = epk16[(size_t)n * 16 + (lane & 15)];
    float a[8] = {0,0,0,0,0,0,0,0};
    if (beta != 0.f) {
        uint4 ua = ((const uint4*)(srcA + (size_t)n * F))[lane];
        unpack8h(ua, a);
    }

    // broadcast all 16 (col, val); cols masked to strip the overflow flag
    int   c[16]; float v[16];
    #pragma unroll
    for (int r = 0; r < 16; ++r) {
        c[r] = __builtin_amdgcn_readlane(my.x, r) & 0xFFFF;
        v[r] = __int_as_float(__builtin_amdgcn_readlane(my.y, r));
    }

    // round 2: one burst of 16 gathers (16 KB in flight per wave)
    uint4 g[16];
    #pragma unroll
    for (int r = 0; r < 16; ++r)
        g[r] = ((const uint4*)(srcB + (size_t)c[r] * F))[lane];

    float acc0[8] = {0,0,0,0,0,0,0,0};
    float acc1[8] = {0,0,0,0,0,0,0,0};
    #pragma unroll
    for (int r = 0; r < 16; r += 2) {
        float b0[8], b1[8];
        unpack8h(g[r], b0);
        unpack8h(g[r + 1], b1);
        #pragma unroll
        for (int i = 0; i < 8; ++i) {
            acc0[i] += v[r]     * b0[i];
            acc1[i] += v[r + 1] * b1[i];
        }
    }

    // rare overflow: >16 real edges — walk the original CSR from entry 16
    if (__builtin_amdgcn_readlane(my.x, 15) & OVFL_FLAG) {
        int s = row_ptr[n], e_end = row_ptr[n + 1];
        for (int e = s + 16; e < e_end; e += 8) {
            int2 m2 = cpack[e + (lane & 7)];
            #pragma unroll
            for (int r = 0; r < 8; ++r) {
                int   cc = __builtin_amdgcn_readlane(m2.x, r);
                float vv = __int_as_float(__builtin_amdgcn_readlane(m2.y, r));
                uint4 gg = ((const uint4*)(srcB + (size_t)cc * F))[lane];
                float bb[8];
                unpack8h(gg, bb);
                #pragma unroll
                for (int i = 0; i < 8; ++i) acc0[i] += vv * bb[i];
            }
        }
    }

    float y[8];
    #pragma unroll
    for (int i = 0; i < 8; ++i)
        y[i] = alpha * (acc0[i] + acc1[i]) + beta * a[i];

    ((uint4*)(dst + (size_t)n * F))[lane] = pack8h(y);
}

// ---------------- MFMA projection over a chunk (kcnt <= K_S), f16 ----------
// per wave: one node; tile M=32(bt) x N=32(cout), K=kcnt*16.
// A: m=L&31, kk=8*(L>>5)+j ; C/D: col=L&31, row=(reg&3)+8*(reg>>2)+4*(L>>5)

__global__ __launch_bounds__(256) void proj_mfma_kernel(
        const u16* __restrict__ ring, int R, int k0, int kcnt,
        const u16* __restrict__ wtfrag, float* __restrict__ out, int accumulate) {
    const int lane = threadIdx.x & 63;
    const int n = (blockIdx.x << 2) + (threadIdx.x >> 6);
    if (n >= N_NODES) return;
    const int col = lane & 31;
    const int grp = lane >> 5;
    const size_t aoff = (size_t)n * F + (size_t)col * 16 + grp * 8;

    union U { uint4 u; half8 h; };
    float16 acc0 = {};
    float16 acc1 = {};
    int j = 0;
    for (; j + 2 <= kcnt; j += 2) {
        int ka = k0 + j, kb = k0 + j + 1;
        U a0, b0, a1, b1;
        a0.u = *(const uint4*)(ring + (size_t)(ka % R) * RING_ELEMS + aoff);
        b0.u = *(const uint4*)(wtfrag + (size_t)ka * 512 + lane * 8);
        a1.u = *(const uint4*)(ring + (size_t)(kb % R) * RING_ELEMS + aoff);
        b1.u = *(const uint4*)(wtfrag + (size_t)kb * 512 + lane * 8);
        acc0 = __builtin_amdgcn_mfma_f32_32x32x16_f16(a0.h, b0.h, acc0, 0, 0, 0);
        acc1 = __builtin_amdgcn_mfma_f32_32x32x16_f16(a1.h, b1.h, acc1, 0, 0, 0);
    }
    if (j < kcnt) {
        int ka = k0 + j;
        U a0, b0;
        a0.u = *(const uint4*)(ring + (size_t)(ka % R) * RING_ELEMS + aoff);
        b0.u = *(const uint4*)(wtfrag + (size_t)ka * 512 + lane * 8);
        acc0 = __builtin_amdgcn_mfma_f32_32x32x16_f16(a0.h, b0.h, acc0, 0, 0, 0);
    }

    #pragma unroll
    for (int r = 0; r < 16; ++r) {
        int bt = (r & 3) + 8 * (r >> 2) + 4 * grp;
        float* op = out + ((size_t)bt * N_NODES + n) * C_OUT + col;
        float val = acc0[r] + acc1[r];
        if (accumulate) *op += val;
        else            *op  = val;
    }
}

// ---------------- host launch ----------------

extern "C" void kernel_launch(void* const* d_in, const int* in_sizes, int n_in,
                              void* d_out, int out_size, void* d_ws, size_t ws_size,
                              hipStream_t stream) {
    const float* x    = (const float*)d_in[0];
    const int*   erow = (const int*)  d_in[1];
    const int*   ecol = (const int*)  d_in[2];
    const float* eval = (const float*)d_in[3];
    const float* W    = (const float*)d_in[4];
    float* out = (float*)d_out;

    char* ws = (char*)d_ws;
    size_t o = 0;
    auto alloc = [&](size_t bytes) -> char* {
        o = (o + 511) & ~(size_t)511;
        char* r = ws + o;
        o += bytes;
        return r;
    };
    int*   cnt     = (int*)  alloc((size_t)N_NODES * 4);
    int*   row_ptr = (int*)  alloc((size_t)(N_NODES + 1) * 4);
    int*   cursor  = (int*)  alloc((size_t)N_NODES * 4);
    int2*  cpack   = (int2*) alloc((size_t)NNZ_PAD_MAX * 8);
    int2*  epk16   = (int2*) alloc((size_t)N_NODES * 16 * 8);
    u16*   wtfrag  = (u16*)  alloc((size_t)K_S * 512 * 2);

    // ring gets everything that's left; R = 20 -> single proj pass,
    // gracefully degrades to chunked passes on smaller workspaces.
    o = (o + 511) & ~(size_t)511;
    int R = (int)((ws_size - o) / RING_BYTES);
    if (R > K_S) R = K_S;
    if (R < 3)  R = 3;
    u16* ring = (u16*)(ws + o);
    auto slot = [&](int k) -> u16* { return ring + (size_t)(k % R) * RING_ELEMS; };

    // CSR build: 5 parallel kernels (T0 transform folded into finalize)
    init_kernel<<<(N_NODES + K_S * 512 + 255) / 256, 256, 0, stream>>>(W, cnt, wtfrag);
    count_kernel<<<(NNZ_E + 255) / 256, 256, 0, stream>>>(erow, cnt);
    scan_kernel<<<1, 256, 0, stream>>>(cnt, row_ptr, cursor);
    scatter_kernel<<<(NNZ_E + 255) / 256, 256, 0, stream>>>(erow, ecol, eval, cursor, cpack);
    finalize_kernel<<<(N_NODES + 3) / 4, 256, 0, stream>>>(
        row_ptr, cursor, cpack, epk16, x, slot(0));

    const int grid4 = (N_NODES + 3) / 4;
    int c0 = 0;
    auto maybe_pass = [&](int k_done) {
        int target = K_S - c0;
        if (target > R) target = R;   // chunk == R safe (stream-ordered)
        if (target > 0 && (k_done - c0 + 1) == target) {
            proj_mfma_kernel<<<grid4, 256, 0, stream>>>(
                ring, R, c0, target, wtfrag, out, (c0 > 0) ? 1 : 0);
            c0 += target;
        }
    };

    maybe_pass(0);

    // T1 = L T0 ; Tk = 2 L T_{k-1} - T_{k-2}
    for (int k = 1; k < K_S; ++k) {
        const u16* srcB = slot(k - 1);
        const u16* srcA = (k >= 2) ? slot(k - 2) : slot(k - 1);  // unread when beta==0
        float alpha = (k == 1) ? 1.f : 2.f;
        float beta  = (k == 1) ? 0.f : -1.f;
        spmm16_kernel<<<grid4, 256, 0, stream>>>(
            srcB, srcA, slot(k), epk16, row_ptr, cpack, alpha, beta);
        maybe_pass(k);
    }
}